// Round 5
// baseline (509.895 us; speedup 1.0000x reference)
//
#include <hip/hip_runtime.h>

// Attn_Pred_Model: 8-tap decayed shift-sum along S + biases, masked.
// x: [16,16,4096,64] fp32. Register sliding-window over S with chunked
// 8-row prefetch (MLP), analytic mask/arange2, masked-strip zero-fill skip,
// 2x block oversubscription for backfill behind fast zero-strips.
//
// Analytic identities (S=4096, BUCKET=64, BUCKETS_MIN=2):
//   arange2[s,j] = ((s - 64j) mod 4096) // 64 = ((s>>6) - j) & 63
//   mask[s,j]    = (s >= 128) && (j < s>>6)
// q = s>>6 is constant within a 16-row strip aligned to 16 ((s0&63)+15 < 64).

#define S_DIM 4096
#define PAST 8
#define RROWS 16                      // rows per thread
#define CHUNK 8                       // rows loaded/computed per chunk
#define NCHUNK (RROWS / CHUNK)        // 2
#define STRIPS 16                     // strips per 256-thread block
#define BLOCK_ROWS (RROWS * STRIPS)   // 256 rows per block
#define BLOCKS_PER_PLANE (S_DIM / BLOCK_ROWS)  // 16

typedef float v4f __attribute__((ext_vector_type(4)));

__global__ __launch_bounds__(256) void attn_pred_kernel(
    const float* __restrict__ x,
    const float* __restrict__ pb_fwd,
    const float* __restrict__ pb_bwd,
    const float* __restrict__ alpha_p,
    const float* __restrict__ beta_p,
    float* __restrict__ out)
{
    const int j4 = threadIdx.x & 15;          // float4 index along B
    const int st = threadIdx.x >> 4;          // strip within block
    const int bh = blockIdx.x >> 4;           // 16 blocks per [S,B] plane
    const int s0 = (blockIdx.x & 15) * BLOCK_ROWS + st * RROWS;
    const int q  = s0 >> 6;                   // strip-constant bucket row
    const int jb = j4 << 2;                   // first j of this float4

    const size_t plane = (size_t)bh * (S_DIM * 16);   // in v4f units
    const v4f* xp = (const v4f*)x + plane;
    v4f*       op = (v4f*)out + plane;

    // Fully-masked strip: write zeros, no loads.
    if (s0 < 128 || jb >= q) {
        const v4f z = (v4f){0.f, 0.f, 0.f, 0.f};
        #pragma unroll
        for (int r = 0; r < RROWS; ++r)
            __builtin_nontemporal_store(z, &op[(s0 + r) * 16 + j4]);
        return;
    }

    // s0 >= 128 > PAST: no s<0 guard needed.
    const float alpha = alpha_p[0];
    const float beta  = beta_p[0];
    float c[PAST];
    c[0] = alpha;
    #pragma unroll
    for (int i = 1; i < PAST; ++i) c[i] = c[i - 1] * beta;

    const v4f bf = ((const v4f*)pb_fwd)[j4];
    v4f bias;
    bias.x = bf.x + pb_bwd[(q - jb    ) & 63];
    bias.y = bf.y + pb_bwd[(q - jb - 1) & 63];
    bias.z = bf.z + pb_bwd[(q - jb - 2) & 63];
    bias.w = bf.w + pb_bwd[(q - jb - 3) & 63];

    v4f mk;
    mk.x = 1.f;                               // jb < q guaranteed
    mk.y = (jb + 1 < q) ? 1.f : 0.f;
    mk.z = (jb + 2 < q) ? 1.f : 0.f;
    mk.w = (jb + 3 < q) ? 1.f : 0.f;

    // Window: w[t] = x[sb - PAST + t], t=0..7 (the 8 rows before the chunk).
    v4f w[PAST];
    #pragma unroll
    for (int t = 0; t < PAST; ++t)
        w[t] = xp[(s0 - PAST + t) * 16 + j4];

    #pragma unroll
    for (int ch = 0; ch < NCHUNK; ++ch) {
        const int sb = s0 + ch * CHUNK;

        // 8 independent loads issued together -> 8 outstanding.
        v4f n[CHUNK];
        #pragma unroll
        for (int k = 0; k < CHUNK; ++k)
            n[k] = xp[(sb + k) * 16 + j4];

        #pragma unroll
        for (int k = 0; k < CHUNK; ++k) {
            v4f acc = (v4f){0.f, 0.f, 0.f, 0.f};
            #pragma unroll
            for (int i = 0; i < PAST; ++i) {
                const int m = k - 1 - i;              // row offset from sb, in [-8, 6]
                const v4f t = (m < 0) ? w[PAST + m] : n[m];
                acc += c[i] * t;
            }
            const v4f o = (acc + bias) * mk;
            __builtin_nontemporal_store(o, &op[(sb + k) * 16 + j4]);
        }

        // Slide window: rows (sb+CHUNK)-8 .. (sb+CHUNK)-1 = sb..sb+7 = n[0..7].
        #pragma unroll
        for (int t = 0; t < PAST; ++t)
            w[t] = n[t];
    }
}

extern "C" void kernel_launch(void* const* d_in, const int* in_sizes, int n_in,
                              void* d_out, int out_size, void* d_ws, size_t ws_size,
                              hipStream_t stream) {
    const float* x       = (const float*)d_in[0];
    const float* pb_fwd  = (const float*)d_in[1];
    const float* pb_bwd  = (const float*)d_in[2];
    const float* alpha_p = (const float*)d_in[3];
    const float* beta_p  = (const float*)d_in[4];
    // d_in[5] = arange2 (int64), d_in[6] = mask -- computed analytically
    float* out = (float*)d_out;

    const int grid = 16 * 16 * BLOCKS_PER_PLANE;  // 4096 blocks x 256 threads
    attn_pred_kernel<<<grid, 256, 0, stream>>>(x, pb_fwd, pb_bwd, alpha_p,
                                               beta_p, out);
}